// Round 17
// baseline (46.276 us; speedup 1.0000x reference)
//
#include <hip/hip_runtime.h>

typedef int   v8i    __attribute__((ext_vector_type(8)));
typedef float f32x16 __attribute__((ext_vector_type(16)));

#define NI 256
#define NT 256
#define NL 32
#define NE 128
#define HW 49
#define NEG_INF (-3.0e38f)
#define SCALE1 0x7F7F7F7F   // e8m0 = 127 -> x1.0, all blocks

// ws layout (fp8 e4m3, MFMA 32x32x64 fragment-linear), validated R15:
//  wsA: frag gw = (i*2+mt)*2+ks, byte j of lane l
//       = img[i, e = ks*64+(l>>5)*32+j, hw = min(mt*32+(l&31),48)]    (2 MB)
//  wsB: frag gw = t*2+ks, byte j of lane l
//       = txt[t, l_word = l&31, e = ks*64+(l>>5)*32+j]                (1 MB)
// A and B use the SAME k<->(lane,byte) map -> k-permutation cancels.

__device__ __forceinline__ unsigned char f32_to_e4m3(float f)
{
    unsigned fb = __float_as_uint(f);
    unsigned s  = (fb >> 24) & 0x80;
    int      e  = (int)((fb >> 23) & 0xFF);
    unsigned m  = fb & 0x7FFFFF;
    int ne = e - 120;                    // e - 127 + 7
    if (ne <= 0)  return (unsigned char)s;          // flush tiny -> +-0
    if (ne > 15) { ne = 15; m = 0x600000; }         // huge -> max (won't occur)
    unsigned base = ((unsigned)ne << 3) | (m >> 20);
    unsigned rem  = m & 0xFFFFF;
    if (rem > 0x80000 || (rem == 0x80000 && (base & 1))) base++;   // RNE
    if (base > 0x7E) base = 0x7E;                   // saturate to 448
    return (unsigned char)(s | base);
}

// ---------- pre-kernel: fp32 -> fp8 MFMA-fragment layout ----------
__global__ __launch_bounds__(256, 4)
void prep_kernel(const float* __restrict__ img,
                 const float* __restrict__ txt,
                 unsigned char* __restrict__ wsA,
                 unsigned char* __restrict__ wsB)
{
    const int tid  = threadIdx.x;
    const int wave = tid >> 6, lane = tid & 63;
    const int ml   = lane & 31, h = lane >> 5;
    const int bid  = blockIdx.x;
    union { unsigned char b[32]; int4 v[2]; } u;
    if (bid < 256) {                        // A-part: 1024 waves
        int gw = bid * 4 + wave;            // (i, mt, ks)
        int i  = gw >> 2, mt = (gw >> 1) & 1, ks = gw & 1;
        int m  = mt * 32 + ml; if (m > HW - 1) m = HW - 1;
        int e0 = ks * 64 + h * 32;
        const float* p = img + ((size_t)i * NE + e0) * HW + m;
        #pragma unroll
        for (int j = 0; j < 32; ++j) u.b[j] = f32_to_e4m3(p[j * HW]);
        int4* dst = (int4*)(wsA + (size_t)gw * 2048 + lane * 32);
        dst[0] = u.v[0]; dst[1] = u.v[1];
    } else {                                // B-part: 512 waves
        int gw = (bid - 256) * 4 + wave;    // (t, ks)
        int t  = gw >> 1, ks = gw & 1;
        int e0 = ks * 64 + h * 32;
        const float* p = txt + ((size_t)t * NL + ml) * NE + e0;
        #pragma unroll
        for (int q = 0; q < 8; ++q) {
            float4 f = *(const float4*)(p + q * 4);
            u.b[q*4+0] = f32_to_e4m3(f.x); u.b[q*4+1] = f32_to_e4m3(f.y);
            u.b[q*4+2] = f32_to_e4m3(f.z); u.b[q*4+3] = f32_to_e4m3(f.w);
        }
        int4* dst = (int4*)(wsB + (size_t)gw * 2048 + lane * 32);
        dst[0] = u.v[0]; dst[1] = u.v[1];
    }
}

// ---------- main kernel: MX-fp8 K=64, 4 MFMA per wave-text (R15) ----------
__global__ __launch_bounds__(256, 4)
void clip_match_kernel(const unsigned char* __restrict__ wsA,
                       const unsigned char* __restrict__ wsB,
                       const int* __restrict__ tlen,
                       const float* __restrict__ nlt,
                       float* __restrict__ out)
{
    const int tid  = threadIdx.x;
    const int wave = tid >> 6, lane = tid & 63;
    const int ml   = lane & 31, h = lane >> 5;
    const int tb   = blockIdx.x & 15;    // text chunk (16 texts)
    const int ig   = blockIdx.x >> 4;    // image group (4 images)
    const int im   = ig * 4 + wave;      // this wave's image

    __shared__ __align__(16) float colmax[4][16][68];   // ~17 KB, wave-private

    // ---- A fragments: 4 x v8i = 32 VGPR ----
    const unsigned char* pa = wsA + (size_t)im * 8192 + lane * 32;
    v8i aA0 = *(const v8i*)(pa);            // mt0 ks0
    v8i aA1 = *(const v8i*)(pa + 2048);     // mt0 ks1
    v8i aB0 = *(const v8i*)(pa + 4096);     // mt1 ks0
    v8i aB1 = *(const v8i*)(pa + 6144);     // mt1 ks1

    const unsigned char* csrc = wsB + (size_t)tb * 16 * 4096 + lane * 32;
#define BFR(t, k) (*(const v8i*)(csrc + (size_t)(t) * 4096 + (k) * 2048))

#define COMPUTE(bk0, bk1, t)                                                \
    {                                                                       \
        f32x16 acc0 = __builtin_amdgcn_mfma_scale_f32_32x32x64_f8f6f4(      \
            aA0, bk0, (f32x16)(0.f), 0, 0, 0, SCALE1, 0, SCALE1);           \
        acc0 = __builtin_amdgcn_mfma_scale_f32_32x32x64_f8f6f4(             \
            aA1, bk1, acc0, 0, 0, 0, SCALE1, 0, SCALE1);                    \
        f32x16 acc1 = __builtin_amdgcn_mfma_scale_f32_32x32x64_f8f6f4(      \
            aB0, bk0, (f32x16)(0.f), 0, 0, 0, SCALE1, 0, SCALE1);           \
        acc1 = __builtin_amdgcn_mfma_scale_f32_32x32x64_f8f6f4(             \
            aB1, bk1, acc1, 0, 0, 0, SCALE1, 0, SCALE1);                    \
        float t0[8];                                                        \
        _Pragma("unroll")                                                   \
        for (int k = 0; k < 8; ++k) t0[k] = fmaxf(acc0[2*k], acc0[2*k+1]);  \
        float t1[4];                                                        \
        _Pragma("unroll")                                                   \
        for (int k = 0; k < 4; ++k) t1[k] = fmaxf(t0[2*k], t0[2*k+1]);      \
        float a0m = fmaxf(fmaxf(t1[0], t1[1]), fmaxf(t1[2], t1[3]));        \
        float u0[4];                                                        \
        _Pragma("unroll")                                                   \
        for (int k = 0; k < 4; ++k) u0[k] = fmaxf(acc1[2*k], acc1[2*k+1]);  \
        float a1m = fmaxf(fmaxf(u0[0], u0[1]), fmaxf(u0[2], u0[3]));        \
        float ex  = (h == 0) ? acc1[8] : NEG_INF;                           \
        colmax[wave][t][lane] = fmaxf(fmaxf(a0m, a1m), ex);                 \
    }

    v8i c0 = BFR(0, 0), c1 = BFR(0, 1);
    #pragma unroll 1
    for (int it = 0; it < 8; ++it) {
        const int t = 2 * it;
        v8i n0 = BFR(t + 1, 0), n1 = BFR(t + 1, 1);
        COMPUTE(c0, c1, t)
        if (it < 7) { c0 = BFR(t + 2, 0); c1 = BFR(t + 2, 1); }
        COMPUTE(n0, n1, t + 1)
    }
#undef COMPUTE
#undef BFR

    // ---- epilogue: merge h-halves, sum 32 cols, write both mirrors ----
    {
        const float scale = expf(nlt[0]);
        const int t = lane & 15;             // text within chunk
        const int q = lane >> 4;             // col octet 0..3
        const float* r0 = &colmax[wave][t][q * 8];        // h-part 0
        const float* r1 = &colmax[wave][t][32 + q * 8];   // h-part 1
        float4 a0 = *(const float4*)(r0 + 0);
        float4 a1 = *(const float4*)(r0 + 4);
        float4 c0 = *(const float4*)(r1 + 0);
        float4 c1 = *(const float4*)(r1 + 4);
        float s = (fmaxf(a0.x, c0.x) + fmaxf(a0.y, c0.y))
                + (fmaxf(a0.z, c0.z) + fmaxf(a0.w, c0.w))
                + (fmaxf(a1.x, c1.x) + fmaxf(a1.y, c1.y))
                + (fmaxf(a1.z, c1.z) + fmaxf(a1.w, c1.w));
        s += __shfl_xor(s, 16);
        s += __shfl_xor(s, 32);              // sum over all 4 octets
        if (q == 0) {
            int tg = tb * 16 + t;
            float v = s * scale / (float)tlen[tg];
            out[im * NT + tg] = v;              // logits_per_image[i,t]
            out[NI * NT + tg * NI + im] = v;    // logits_per_text[t,i]
        }
    }
}

extern "C" void kernel_launch(void* const* d_in, const int* in_sizes, int n_in,
                              void* d_out, int out_size, void* d_ws, size_t ws_size,
                              hipStream_t stream)
{
    const float* img  = (const float*)d_in[0];
    const float* txt  = (const float*)d_in[1];
    const int*   tlen = (const int*)d_in[2];
    const float* nlt  = (const float*)d_in[3];
    float* out = (float*)d_out;

    unsigned char* wsA = (unsigned char*)d_ws;           // 2 MB
    unsigned char* wsB = wsA + (size_t)2 * 1024 * 1024;  // 1 MB

    prep_kernel<<<dim3(384), dim3(256), 0, stream>>>(img, txt, wsA, wsB);
    // DIFFERENTIAL PROBE: main launched TWICE (idempotent, deterministic).
    // main_time = dur(this round) - dur(R15=32.5us). Fork pre-committed in
    // the journal: ~58us -> anomaly is inside main; ~40us -> overhead/prep
    // dominates and R18 fuses to a single launch.
    clip_match_kernel<<<dim3(1024), dim3(256), 0, stream>>>(wsA, wsB, tlen, nlt, out);
    clip_match_kernel<<<dim3(1024), dim3(256), 0, stream>>>(wsA, wsB, tlen, nlt, out);
}

// Round 19
// 29.136 us; speedup vs baseline: 1.5883x; 1.5883x over previous
//
#include <hip/hip_runtime.h>

typedef int   v8i    __attribute__((ext_vector_type(8)));
typedef float f32x16 __attribute__((ext_vector_type(16)));

#define NI 256
#define NT 256
#define NL 32
#define NE 128
#define HW 49
#define NEG_INF (-3.0e38f)
#define SCALE1 0x7F7F7F7F   // e8m0 = 127 -> x1.0, all blocks

// ws layout (fp8 e4m3, MFMA 32x32x64 fragment-linear), validated R15-R17:
//  wsA: frag gw = (i*2+mt)*2+ks, byte j of lane l
//       = img[i, e = ks*64+(l>>5)*32+j, hw = min(mt*32+(l&31),48)]    (2 MB)
//  wsB: frag gw = t*2+ks, byte j of lane l
//       = txt[t, l_word = l&31, e = ks*64+(l>>5)*32+j]                (1 MB)
// A and B use the SAME k<->(lane,byte) map -> k-permutation cancels.

__device__ __forceinline__ unsigned char f32_to_e4m3(float f)
{
    unsigned fb = __float_as_uint(f);
    unsigned s  = (fb >> 24) & 0x80;
    int      e  = (int)((fb >> 23) & 0xFF);
    unsigned m  = fb & 0x7FFFFF;
    int ne = e - 120;                    // e - 127 + 7
    if (ne <= 0)  return (unsigned char)s;          // flush tiny -> +-0
    if (ne > 15) { ne = 15; m = 0x600000; }         // huge -> max (won't occur)
    unsigned base = ((unsigned)ne << 3) | (m >> 20);
    unsigned rem  = m & 0xFFFFF;
    if (rem > 0x80000 || (rem == 0x80000 && (base & 1))) base++;   // RNE
    if (base > 0x7E) base = 0x7E;                   // saturate to 448
    return (unsigned char)(s | base);
}

// ---------- pre-kernel v2: WHOLE-CHIP spread (1280 blocks, 5/CU) ----------
// R17 differential says prep+gap = 18.7us; R15's prep used only 96 CUs.
// A-part: 1024 blocks, one frag-group each; wave w converts j-slice
// [w*8, w*8+8) -> 8 strided loads + ~80 VALU per wave.
// B-part: 256 blocks, 2 frag-groups each; wave converts a 16-byte e-slice
// via 4 coalesced float4 loads.
__global__ __launch_bounds__(256, 4)
void prep_kernel(const float* __restrict__ img,
                 const float* __restrict__ txt,
                 unsigned char* __restrict__ wsA,
                 unsigned char* __restrict__ wsB)
{
    const int tid  = threadIdx.x;
    const int wave = tid >> 6, lane = tid & 63;
    const int ml   = lane & 31, h = lane >> 5;
    const int bid  = blockIdx.x;
    if (bid < 1024) {                       // A-part: one gw per block
        int gw = bid;                       // (i, mt, ks)
        int i  = gw >> 2, mt = (gw >> 1) & 1, ks = gw & 1;
        int m  = mt * 32 + ml; if (m > HW - 1) m = HW - 1;
        int e0 = ks * 64 + h * 32 + wave * 8;     // this wave's 8-e slice
        const float* p = img + ((size_t)i * NE + e0) * HW + m;
        union { unsigned char b[8]; int2 v; } u;
        #pragma unroll
        for (int j = 0; j < 8; ++j) u.b[j] = f32_to_e4m3(p[j * HW]);
        *(int2*)(wsA + (size_t)gw * 2048 + lane * 32 + wave * 8) = u.v;
    } else {                                // B-part: 2 gw per block
        int bb = bid - 1024;                // 0..255
        int gw = bb * 2 + (wave >> 1);      // (t, ks)
        int eh = wave & 1;                  // 16-byte e-half within the slice
        int t  = gw >> 1, ks = gw & 1;
        int e0 = ks * 64 + h * 32 + eh * 16;
        const float* p = txt + ((size_t)t * NL + ml) * NE + e0;
        union { unsigned char b[16]; int4 v; } u;
        #pragma unroll
        for (int q = 0; q < 4; ++q) {
            float4 f = *(const float4*)(p + q * 4);
            u.b[q*4+0] = f32_to_e4m3(f.x); u.b[q*4+1] = f32_to_e4m3(f.y);
            u.b[q*4+2] = f32_to_e4m3(f.z); u.b[q*4+3] = f32_to_e4m3(f.w);
        }
        *(int4*)(wsB + (size_t)gw * 2048 + lane * 32 + eh * 16) = u.v;
    }
}

// ---------- main kernel: MX-fp8 K=64, 4 MFMA per wave-text (R15 exact) ----------
__global__ __launch_bounds__(256, 4)
void clip_match_kernel(const unsigned char* __restrict__ wsA,
                       const unsigned char* __restrict__ wsB,
                       const int* __restrict__ tlen,
                       const float* __restrict__ nlt,
                       float* __restrict__ out)
{
    const int tid  = threadIdx.x;
    const int wave = tid >> 6, lane = tid & 63;
    const int ml   = lane & 31, h = lane >> 5;
    const int tb   = blockIdx.x & 15;    // text chunk (16 texts)
    const int ig   = blockIdx.x >> 4;    // image group (4 images)
    const int im   = ig * 4 + wave;      // this wave's image

    __shared__ __align__(16) float colmax[4][16][68];   // ~17 KB, wave-private

    // ---- A fragments: 4 x v8i = 32 VGPR ----
    const unsigned char* pa = wsA + (size_t)im * 8192 + lane * 32;
    v8i aA0 = *(const v8i*)(pa);            // mt0 ks0
    v8i aA1 = *(const v8i*)(pa + 2048);     // mt0 ks1
    v8i aB0 = *(const v8i*)(pa + 4096);     // mt1 ks0
    v8i aB1 = *(const v8i*)(pa + 6144);     // mt1 ks1

    const unsigned char* csrc = wsB + (size_t)tb * 16 * 4096 + lane * 32;
#define BFR(t, k) (*(const v8i*)(csrc + (size_t)(t) * 4096 + (k) * 2048))

#define COMPUTE(bk0, bk1, t)                                                \
    {                                                                       \
        f32x16 acc0 = __builtin_amdgcn_mfma_scale_f32_32x32x64_f8f6f4(      \
            aA0, bk0, (f32x16)(0.f), 0, 0, 0, SCALE1, 0, SCALE1);           \
        acc0 = __builtin_amdgcn_mfma_scale_f32_32x32x64_f8f6f4(             \
            aA1, bk1, acc0, 0, 0, 0, SCALE1, 0, SCALE1);                    \
        f32x16 acc1 = __builtin_amdgcn_mfma_scale_f32_32x32x64_f8f6f4(      \
            aB0, bk0, (f32x16)(0.f), 0, 0, 0, SCALE1, 0, SCALE1);           \
        acc1 = __builtin_amdgcn_mfma_scale_f32_32x32x64_f8f6f4(             \
            aB1, bk1, acc1, 0, 0, 0, SCALE1, 0, SCALE1);                    \
        /* partial max over this h-half's rows; C/D (shape-determined):    \
           col=lane&31, row r2=(reg&3)+8*(reg>>2)+4*h; acc0: m=r2 (all     \
           16 valid); acc1: m=32+r2 -> regs 0..7, +reg8 (m=48) iff h==0 */ \
        float t0[8];                                                        \
        _Pragma("unroll")                                                   \
        for (int k = 0; k < 8; ++k) t0[k] = fmaxf(acc0[2*k], acc0[2*k+1]);  \
        float t1[4];                                                        \
        _Pragma("unroll")                                                   \
        for (int k = 0; k < 4; ++k) t1[k] = fmaxf(t0[2*k], t0[2*k+1]);      \
        float a0m = fmaxf(fmaxf(t1[0], t1[1]), fmaxf(t1[2], t1[3]));        \
        float u0[4];                                                        \
        _Pragma("unroll")                                                   \
        for (int k = 0; k < 4; ++k) u0[k] = fmaxf(acc1[2*k], acc1[2*k+1]);  \
        float a1m = fmaxf(fmaxf(u0[0], u0[1]), fmaxf(u0[2], u0[3]));        \
        float ex  = (h == 0) ? acc1[8] : NEG_INF;                           \
        colmax[wave][t][lane] = fmaxf(fmaxf(a0m, a1m), ex);                 \
    }

    v8i c0 = BFR(0, 0), c1 = BFR(0, 1);
    #pragma unroll 1
    for (int it = 0; it < 8; ++it) {
        const int t = 2 * it;
        v8i n0 = BFR(t + 1, 0), n1 = BFR(t + 1, 1);
        COMPUTE(c0, c1, t)
        if (it < 7) { c0 = BFR(t + 2, 0); c1 = BFR(t + 2, 1); }
        COMPUTE(n0, n1, t + 1)
    }
#undef COMPUTE
#undef BFR

    // ---- epilogue: merge h-halves, sum 32 cols, write both mirrors ----
    {
        const float scale = expf(nlt[0]);
        const int t = lane & 15;             // text within chunk
        const int q = lane >> 4;             // col octet 0..3
        const float* r0 = &colmax[wave][t][q * 8];        // h-part 0
        const float* r1 = &colmax[wave][t][32 + q * 8];   // h-part 1
        float4 a0 = *(const float4*)(r0 + 0);
        float4 a1 = *(const float4*)(r0 + 4);
        float4 c0 = *(const float4*)(r1 + 0);
        float4 c1 = *(const float4*)(r1 + 4);
        float s = (fmaxf(a0.x, c0.x) + fmaxf(a0.y, c0.y))
                + (fmaxf(a0.z, c0.z) + fmaxf(a0.w, c0.w))
                + (fmaxf(a1.x, c1.x) + fmaxf(a1.y, c1.y))
                + (fmaxf(a1.z, c1.z) + fmaxf(a1.w, c1.w));
        s += __shfl_xor(s, 16);
        s += __shfl_xor(s, 32);              // sum over all 4 octets
        if (q == 0) {
            int tg = tb * 16 + t;
            float v = s * scale / (float)tlen[tg];
            out[im * NT + tg] = v;              // logits_per_image[i,t]
            out[NI * NT + tg * NI + im] = v;    // logits_per_text[t,i]
        }
    }
}

extern "C" void kernel_launch(void* const* d_in, const int* in_sizes, int n_in,
                              void* d_out, int out_size, void* d_ws, size_t ws_size,
                              hipStream_t stream)
{
    const float* img  = (const float*)d_in[0];
    const float* txt  = (const float*)d_in[1];
    const int*   tlen = (const int*)d_in[2];
    const float* nlt  = (const float*)d_in[3];
    float* out = (float*)d_out;

    unsigned char* wsA = (unsigned char*)d_ws;           // 2 MB
    unsigned char* wsB = wsA + (size_t)2 * 1024 * 1024;  // 1 MB

    prep_kernel<<<dim3(1280), dim3(256), 0, stream>>>(img, txt, wsA, wsB);
    clip_match_kernel<<<dim3(1024), dim3(256), 0, stream>>>(wsA, wsB, tlen, nlt, out);
}